// Round 8
// baseline (195.980 us; speedup 1.0000x reference)
//
#include <hip/hip_runtime.h>
#include <cstdint>

typedef unsigned long long u64;
typedef unsigned short ushort_t;
typedef __attribute__((ext_vector_type(8))) short short8;
typedef __attribute__((ext_vector_type(4))) float f32x4;

#define B_TOTAL 16384
#define K_DIM   1025
#define O_DIM   1025
#define NWORDS  17        // ceil(1025/64)
#define NKT     34        // K tiles of 32 (covers 1088)
#define NFRAG   72        // n-fragments of 16 (covers 1152)
#define A_BYTES 8192      // per (panel,kt): 4 hi frags + 4 lo frags, 1 KB each
#define B_BYTES 73728     // per kt: 72 frags, 1 KB each
#define STEP_BYTES (A_BYTES + B_BYTES)   // 81920; double-buffered = 160 KB LDS
#define L23_ROWS 16       // b-rows per l2l3 block (1024 blocks -> 4 blocks/CU)

// round-to-nearest-even f32 -> bf16 (finite inputs)
__device__ __forceinline__ ushort_t f2bf_rne(float f) {
  unsigned u = __float_as_uint(f);
  return (ushort_t)((u + 0x7fffu + ((u >> 16) & 1u)) >> 16);
}

// async global->LDS, 16B per lane; LDS dest = wave-uniform base + lane*16
__device__ __forceinline__ void gload16(const ushort_t* g, char* l) {
  __builtin_amdgcn_global_load_lds(
      (const __attribute__((address_space(1))) void*)g,
      (__attribute__((address_space(3))) void*)l, 16, 0, 0);
}

// -------- pack all weight bit-rows (W0|W1|W2) + zero cnt --------
__global__ __launch_bounds__(256) void pack_all_kernel(const float* __restrict__ W0,
                                                       const float* __restrict__ W1,
                                                       const float* __restrict__ W2,
                                                       u64* __restrict__ w0b,
                                                       u64* __restrict__ w1b,
                                                       u64* __restrict__ w2b,
                                                       unsigned* cnt) {
  __shared__ unsigned char by[136];
  const int row = blockIdx.x, t = threadIdx.x;
  if (row == 0 && t == 0) *cnt = 0;
  const float* src; u64* dst; int o;
  if (row < O_DIM)           { src = W0; dst = w0b; o = row; }
  else if (row < 2 * O_DIM)  { src = W1; dst = w1b; o = row - O_DIM; }
  else                       { src = W2; dst = w2b; o = 0; }
  if (t < 136) {
    const float* wr = src + (size_t)o * K_DIM;
    unsigned m = 0;
#pragma unroll
    for (int j = 0; j < 8; ++j) {
      int k = t * 8 + j;
      bool pos = (k < K_DIM) ? (wr[k] >= 0.0f) : true;
      m |= (unsigned)pos << j;
    }
    by[t] = (unsigned char)m;
  }
  __syncthreads();
  if (t < NWORDS) {
    u64 word = 0;
#pragma unroll
    for (int q = 0; q < 8; ++q) word |= (u64)by[t * 8 + q] << (8 * q);
    dst[(size_t)o * NWORDS + t] = word;
  }
}

// -------- prep_sbf: sign(W0) in MFMA-fragment order: [kt][nf][lane][8 shorts] --------
__global__ __launch_bounds__(256) void prep_sbf_kernel(const float* __restrict__ w0,
                                                       ushort_t* __restrict__ sbf) {
  const int t = threadIdx.x;
  const int f = blockIdx.x * 4 + (t >> 6);        // 0..2447 = kt*72+nf
  const int lane = t & 63;
  const int kt = f / NFRAG, nf = f % NFRAG;
  const int o = nf * 16 + (lane & 15);
  const int kbase = kt * 32 + (lane >> 4) * 8;
  short8 sv;
#pragma unroll
  for (int j = 0; j < 8; ++j) {
    int k = kbase + j;
    short v = 0;
    if (o < O_DIM && k < K_DIM)
      v = (short)((w0[(size_t)o * K_DIM + k] >= 0.0f) ? 0x3F80 : 0xBF80);
    sv[j] = v;
  }
  *(short8*)&sbf[(size_t)f * 512 + lane * 8] = sv;
}

// -------- prep_xf: x -> hi/lo bf16 in fragment order + errb --------
__global__ __launch_bounds__(256) void prep_xf_kernel(const float* __restrict__ x,
                                                      ushort_t* __restrict__ xf,
                                                      float* __restrict__ errb) {
  const int p = blockIdx.x, t = threadIdx.x;
  const int mf = t >> 6, lane = t & 63;
  const int lr = lane & 15, lg = lane >> 4;
  const int brow = p * 64 + mf * 16 + lr;
  const float* xr = x + (size_t)brow * K_DIM;
  float s = 0.0f;
  for (int kt = 0; kt < NKT; ++kt) {
    const int kbase = kt * 32 + lg * 8;
    float v[8];
    if (kbase + 8 <= K_DIM) {
      float4 a = *(const float4*)(xr + kbase);
      float4 b = *(const float4*)(xr + kbase + 4);
      v[0]=a.x; v[1]=a.y; v[2]=a.z; v[3]=a.w; v[4]=b.x; v[5]=b.y; v[6]=b.z; v[7]=b.w;
    } else {
#pragma unroll
      for (int j = 0; j < 8; ++j) v[j] = (kbase + j < K_DIM) ? xr[kbase + j] : 0.0f;
    }
    short8 hi, lo;
#pragma unroll
    for (int j = 0; j < 8; ++j) {
      s += fabsf(v[j]);
      ushort_t h = f2bf_rne(v[j]);
      float hf = __uint_as_float((unsigned)h << 16);
      ushort_t l = f2bf_rne(v[j] - hf);
      hi[j] = (short)h; lo[j] = (short)l;
    }
    size_t base = ((size_t)(p * NKT + kt) * 8 + mf) * 512 + lane * 8;
    *(short8*)&xf[base] = hi;
    *(short8*)&xf[base + 4 * 512] = lo;
  }
  s += __shfl_xor(s, 16, 64);
  s += __shfl_xor(s, 32, 64);
  if (lg == 0) errb[brow] = s * (1.02f / 65536.0f) + 0.125f;
}

// -------- layer 1 GEMM: output-stationary, full N per block; counted-vmcnt pipeline --------
__global__ __launch_bounds__(512, 2) void l1_gemm_kernel(
    const ushort_t* __restrict__ xf, const ushort_t* __restrict__ sbf,
    const float* __restrict__ errb, u64* __restrict__ h1b,
    unsigned* __restrict__ cnt, unsigned* __restrict__ list, unsigned cap) {
  extern __shared__ char smem[];
  const int p = blockIdx.x;
  const int t = threadIdx.x;
  const int wave = t >> 6, lane = t & 63;
  const int lr = lane & 15, lg = lane >> 4;
  const int b0 = p * 64;
  const int obase = wave * 144;

  const ushort_t* gA = xf + (size_t)p * NKT * (A_BYTES / 2);

  f32x4 acc[4][9];
#pragma unroll
  for (int mf = 0; mf < 4; ++mf)
#pragma unroll
    for (int nfl = 0; nfl < 9; ++nfl)
#pragma unroll
      for (int c = 0; c < 4; ++c) acc[mf][nfl][c] = 0.0f;

#define STAGE(BUFI, KT)                                                        \
  {                                                                            \
    char* dbuf = smem + (BUFI) * STEP_BYTES;                                   \
    _Pragma("unroll")                                                          \
    for (int i = 0; i < 10; ++i) {                                             \
      int s = wave * 10 + i;                                                   \
      const ushort_t* g = (s < 8)                                              \
          ? gA + (KT) * (A_BYTES / 2) + s * 512 + lane * 8                     \
          : sbf + (size_t)(KT) * (B_BYTES / 2) + (s - 8) * 512 + lane * 8;     \
      gload16(g, dbuf + s * 1024);                                             \
    }                                                                          \
  }

  STAGE(0, 0);
  int cur = 0;
  for (int kt = 0; kt < NKT; ++kt) {
    // issue next tile's loads, then wait ONLY for the current tile (counted vmcnt):
    // 10 newest (next-tile) stay in flight across the barrier; 10 oldest (cur) retired.
    if (kt + 1 < NKT) {
      STAGE(cur ^ 1, kt + 1);
      asm volatile("s_waitcnt vmcnt(10)" ::: "memory");
    } else {
      asm volatile("s_waitcnt vmcnt(0)" ::: "memory");
    }
    __builtin_amdgcn_s_barrier();          // buf[cur] resident block-wide

    const ushort_t* A = (const ushort_t*)(smem + cur * STEP_BYTES);
    const ushort_t* Bf = A + A_BYTES / 2;
    short8 ah[4], al[4];
#pragma unroll
    for (int mf = 0; mf < 4; ++mf) {
      ah[mf] = *(const short8*)&A[mf * 512 + lane * 8];
      al[mf] = *(const short8*)&A[(4 + mf) * 512 + lane * 8];
    }
    __builtin_amdgcn_s_setprio(1);
#pragma unroll
    for (int nfl = 0; nfl < 9; ++nfl) {
      short8 bv = *(const short8*)&Bf[(wave * 9 + nfl) * 512 + lane * 8];
#pragma unroll
      for (int mf = 0; mf < 4; ++mf) {
        acc[mf][nfl] = __builtin_amdgcn_mfma_f32_16x16x32_bf16(ah[mf], bv, acc[mf][nfl], 0, 0, 0);
        acc[mf][nfl] = __builtin_amdgcn_mfma_f32_16x16x32_bf16(al[mf], bv, acc[mf][nfl], 0, 0, 0);
      }
    }
    __builtin_amdgcn_s_setprio(0);
    // all my ds_reads retired before releasing buf[cur] for overwrite (rule #18 fence)
    asm volatile("s_waitcnt lgkmcnt(0)" ::: "memory");
    __builtin_amdgcn_sched_barrier(0);
    __builtin_amdgcn_s_barrier();          // buf[cur] reusable; next-tile loads still in flight
    cur ^= 1;
  }
#undef STAGE

  unsigned char* bits = (unsigned char*)smem;    // [64][1152]
  int* scan = (int*)(smem + 73728);

  float eb[4][4];
#pragma unroll
  for (int mf = 0; mf < 4; ++mf)
#pragma unroll
    for (int rg = 0; rg < 4; ++rg) eb[mf][rg] = errb[b0 + mf * 16 + lg * 4 + rg];

  int myCnt = 0;
#pragma unroll
  for (int mf = 0; mf < 4; ++mf)
#pragma unroll
    for (int nfl = 0; nfl < 9; ++nfl)
#pragma unroll
      for (int rg = 0; rg < 4; ++rg) {
        int bl = mf * 16 + lg * 4 + rg;
        int o  = obase + nfl * 16 + lr;
        float lin = acc[mf][nfl][rg];
        bits[bl * 1152 + o] = (lin >= 0.0f) ? 1u : 0u;
        myCnt += (int)((o < O_DIM) && (fabsf(lin) <= eb[mf][rg]));
      }

  int incl = myCnt;
#pragma unroll
  for (int d = 1; d < 64; d <<= 1) {
    int v = __shfl_up(incl, d, 64);
    if (lane >= d) incl += v;
  }
  if (lane == 63) scan[wave] = incl;
  __syncthreads();
  if (t == 0) {
    int run = 0;
#pragma unroll
    for (int i = 0; i < 8; ++i) { int c = scan[i]; scan[8 + i] = run; run += c; }
    scan[16] = (run > 0) ? (int)atomicAdd(cnt, (unsigned)run) : 0;
  }
  __syncthreads();

  {
    int off = scan[16] + scan[8 + wave] + incl - myCnt;
#pragma unroll
    for (int mf = 0; mf < 4; ++mf)
#pragma unroll
      for (int nfl = 0; nfl < 9; ++nfl)
#pragma unroll
        for (int rg = 0; rg < 4; ++rg) {
          int o = obase + nfl * 16 + lr;
          float lin = acc[mf][nfl][rg];
          if ((o < O_DIM) && (fabsf(lin) <= eb[mf][rg])) {
            int b = b0 + mf * 16 + lg * 4 + rg;
            unsigned abit = (lin >= 0.0f) ? 1u : 0u;
            if ((unsigned)off < cap)
              list[off] = ((unsigned)b << 12) | ((unsigned)o << 1) | abit;
            ++off;
          }
        }
  }

  for (int task = t; task < 64 * NWORDS; task += 512) {
    int row = task / NWORDS, w = task % NWORDS;
    u64 word = 0;
#pragma unroll
    for (int q = 0; q < 8; ++q) {
      u64 v = *(const u64*)&bits[row * 1152 + w * 64 + q * 8];
#pragma unroll
      for (int m = 0; m < 8; ++m)
        word |= ((v >> (8 * m)) & 1ull) << (q * 8 + m);
    }
    int rem = O_DIM - w * 64;
    if (rem < 64) word |= (~0ull << rem);
    h1b[(size_t)(b0 + row) * NWORDS + w] = word;
  }
}

// -------- fixup: exact sequential recompute of flagged elements (bitwise = reference) --------
__global__ void fixup_kernel(const float* __restrict__ x, const u64* __restrict__ w0b,
                             const unsigned* __restrict__ cnt, const unsigned* __restrict__ list,
                             unsigned cap, u64* __restrict__ h1b) {
  unsigned n = *cnt; if (n > cap) n = cap;
  for (unsigned i = blockIdx.x * blockDim.x + threadIdx.x; i < n;
       i += gridDim.x * blockDim.x) {
    unsigned en = list[i];
    int b = (int)(en >> 12), o = (int)((en >> 1) & 0x7ffu);
    unsigned abit = en & 1u;
    const float* xr = x + (size_t)b * K_DIM;
    const u64* wr = w0b + (size_t)o * NWORDS;
    float acc = 0.0f;
    for (int j = 0; j < 16; ++j) {      // k strictly ascending, single accumulator
      u64 wd = wr[j];
#pragma unroll
      for (int m = 0; m < 64; ++m) {
        float v = xr[j * 64 + m];
        unsigned neg = ((unsigned)(wd >> m) & 1u) ^ 1u;
        acc += __uint_as_float(__float_as_uint(v) ^ (neg << 31));
      }
    }
    {
      u64 wd = wr[16];
      float v = xr[1024];
      unsigned neg = ((unsigned)wd & 1u) ^ 1u;
      acc += __uint_as_float(__float_as_uint(v) ^ (neg << 31));
    }
    unsigned nb = (acc >= 0.0f) ? 1u : 0u;
    if (nb != abit)
      atomicXor(&h1b[(size_t)b * NWORDS + (o >> 6)], 1ull << (o & 63));
  }
}

// -------- layers 2+3 fused: XOR+popcount (exact); lean regs + 2-row ILP --------
__global__ __launch_bounds__(256) void l2l3_kernel(const u64* __restrict__ h1b,
                                                   const u64* __restrict__ w1b,
                                                   const u64* __restrict__ w2b,
                                                   float* __restrict__ out) {
  __shared__ u64 hs[L23_ROWS][NWORDS];
  __shared__ u64 h2[L23_ROWS][NWORDS];
  const int bt = blockIdx.x;                 // 1024 blocks x 16 rows
  const int t = threadIdx.x;
  for (int i = t; i < L23_ROWS * NWORDS; i += 256)
    hs[i / NWORDS][i % NWORDS] = h1b[(size_t)(bt * L23_ROWS + i / NWORDS) * NWORDS + i % NWORDS];
  __syncthreads();

  const int w = t >> 6, l = t & 63;
  for (int oc = w; oc < NWORDS; oc += 4) {
    int o = oc * 64 + l;
    bool valid = (o < O_DIM);
    int orow = valid ? o : (O_DIM - 1);
    u64 wb[NWORDS];
#pragma unroll
    for (int j = 0; j < NWORDS; ++j) wb[j] = w1b[(size_t)orow * NWORDS + j];
    for (int b = 0; b < L23_ROWS; b += 2) {   // no unroll: keep regs lean; 2 chains for ILP
      int p0 = 0, p1 = 0;
#pragma unroll
      for (int j = 0; j < NWORDS; ++j) {
        p0 += __popcll(hs[b + 0][j] ^ wb[j]);
        p1 += __popcll(hs[b + 1][j] ^ wb[j]);
      }
      u64 m0 = __ballot(valid ? (K_DIM - 2 * p0 >= 0) : true);
      u64 m1 = __ballot(valid ? (K_DIM - 2 * p1 >= 0) : true);
      if (l == 0) h2[b + 0][oc] = m0;
      if (l == 1) h2[b + 1][oc] = m1;
    }
  }
  __syncthreads();
  if (t < L23_ROWS) {
    int p = 0;
#pragma unroll
    for (int j = 0; j < NWORDS; ++j) p += __popcll(h2[t][j] ^ w2b[j]);
    out[bt * L23_ROWS + t] = ((K_DIM - 2 * p) >= 0) ? 1.0f : 0.0f;
  }
}

extern "C" void kernel_launch(void* const* d_in, const int* in_sizes, int n_in,
                              void* d_out, int out_size, void* d_ws, size_t ws_size,
                              hipStream_t stream) {
  const float* x  = (const float*)d_in[0];
  const float* W0 = (const float*)d_in[1];
  const float* W1 = (const float*)d_in[2];
  const float* W2 = (const float*)d_in[3];
  float* out = (float*)d_out;

  char* ws = (char*)d_ws;
  u64*      w0b  = (u64*)(ws);                   //       0 .. 139776
  u64*      w1b  = (u64*)(ws + 139776);          // .. 279552
  u64*      w2b  = (u64*)(ws + 279552);          // .. 279808
  float*    errb = (float*)(ws + 279808);        // .. 345344
  u64*      h1b  = (u64*)(ws + 345344);          // .. 2573568
  unsigned* cnt  = (unsigned*)(ws + 2573568);    // .. 2573824
  ushort_t* sbf  = (ushort_t*)(ws + 2573824);    // .. 5080576
  ushort_t* xf   = (ushort_t*)(ws + 5080576);    // .. 76383744
  unsigned* list = (unsigned*)(ws + 76383744);
  unsigned  cap  = (ws_size > 76383744 + 4) ? (unsigned)((ws_size - 76383744) / 4) : 0;

  static bool attr_set = false;
  if (!attr_set) {
    hipFuncSetAttribute((const void*)l1_gemm_kernel,
                        hipFuncAttributeMaxDynamicSharedMemorySize, 2 * STEP_BYTES);
    attr_set = true;
  }

  pack_all_kernel<<<2 * O_DIM + 1, 256, 0, stream>>>(W0, W1, W2, w0b, w1b, w2b, cnt);
  prep_sbf_kernel<<<NKT * NFRAG / 4, 256, 0, stream>>>(W0, sbf);
  prep_xf_kernel<<<B_TOTAL / 64, 256, 0, stream>>>(x, xf, errb);
  l1_gemm_kernel<<<B_TOTAL / 64, 512, 2 * STEP_BYTES, stream>>>(
      xf, sbf, errb, h1b, cnt, list, cap);
  fixup_kernel<<<1024, 256, 0, stream>>>(x, w0b, cnt, list, cap, h1b);
  l2l3_kernel<<<B_TOTAL / L23_ROWS, 256, 0, stream>>>(h1b, w1b, w2b, out);
}

// Round 9
// 180.729 us; speedup vs baseline: 1.0844x; 1.0844x over previous
//
#include <hip/hip_runtime.h>
#include <cstdint>

typedef unsigned long long u64;
typedef unsigned short ushort_t;
typedef __attribute__((ext_vector_type(8))) short short8;
typedef __attribute__((ext_vector_type(4))) float f32x4;

#define B_TOTAL 16384
#define K_DIM   1025
#define O_DIM   1025
#define NWORDS  17        // ceil(1025/64)
#define NKT     34        // K tiles of 32 (covers 1088)
#define NFRAG   72        // n-fragments of 16 (covers 1152)
#define A_BYTES 8192      // per (panel,kt): 4 hi frags + 4 lo frags, 1 KB each
#define B_BYTES 73728     // per kt: 72 frags, 1 KB each
#define STEP_BYTES (A_BYTES + B_BYTES)   // 81920; double-buffered = 160 KB LDS
#define FLAG_CAP 4096     // LDS flag list (mean ~225/block; 18x headroom)

// round-to-nearest-even f32 -> bf16 (finite inputs)
__device__ __forceinline__ ushort_t f2bf_rne(float f) {
  unsigned u = __float_as_uint(f);
  return (ushort_t)((u + 0x7fffu + ((u >> 16) & 1u)) >> 16);
}

// async global->LDS, 16B per lane; LDS dest = wave-uniform base + lane*16
__device__ __forceinline__ void gload16(const ushort_t* g, char* l) {
  __builtin_amdgcn_global_load_lds(
      (const __attribute__((address_space(1))) void*)g,
      (__attribute__((address_space(3))) void*)l, 16, 0, 0);
}

// -------- pack all weight bit-rows (W0|W1|W2): bit=1 <=> w>=0, pad bits=1 --------
__global__ __launch_bounds__(256) void pack_all_kernel(const float* __restrict__ W0,
                                                       const float* __restrict__ W1,
                                                       const float* __restrict__ W2,
                                                       u64* __restrict__ w0b,
                                                       u64* __restrict__ w1b,
                                                       u64* __restrict__ w2b) {
  __shared__ unsigned char by[136];
  const int row = blockIdx.x, t = threadIdx.x;
  const float* src; u64* dst; int o;
  if (row < O_DIM)           { src = W0; dst = w0b; o = row; }
  else if (row < 2 * O_DIM)  { src = W1; dst = w1b; o = row - O_DIM; }
  else                       { src = W2; dst = w2b; o = 0; }
  if (t < 136) {
    const float* wr = src + (size_t)o * K_DIM;
    unsigned m = 0;
#pragma unroll
    for (int j = 0; j < 8; ++j) {
      int k = t * 8 + j;
      bool pos = (k < K_DIM) ? (wr[k] >= 0.0f) : true;
      m |= (unsigned)pos << j;
    }
    by[t] = (unsigned char)m;
  }
  __syncthreads();
  if (t < NWORDS) {
    u64 word = 0;
#pragma unroll
    for (int q = 0; q < 8; ++q) word |= (u64)by[t * 8 + q] << (8 * q);
    dst[(size_t)o * NWORDS + t] = word;
  }
}

// -------- prep_sbf: sign(W0) in MFMA-fragment order: [kt][nf][lane][8 shorts] --------
__global__ __launch_bounds__(256) void prep_sbf_kernel(const float* __restrict__ w0,
                                                       ushort_t* __restrict__ sbf) {
  const int t = threadIdx.x;
  const int f = blockIdx.x * 4 + (t >> 6);        // 0..2447 = kt*72+nf
  const int lane = t & 63;
  const int kt = f / NFRAG, nf = f % NFRAG;
  const int o = nf * 16 + (lane & 15);
  const int kbase = kt * 32 + (lane >> 4) * 8;
  short8 sv;
#pragma unroll
  for (int j = 0; j < 8; ++j) {
    int k = kbase + j;
    short v = 0;
    if (o < O_DIM && k < K_DIM)
      v = (short)((w0[(size_t)o * K_DIM + k] >= 0.0f) ? 0x3F80 : 0xBF80);
    sv[j] = v;
  }
  *(short8*)&sbf[(size_t)f * 512 + lane * 8] = sv;
}

// -------- prep_xf: x -> hi/lo bf16 in fragment order + errb --------
__global__ __launch_bounds__(256) void prep_xf_kernel(const float* __restrict__ x,
                                                      ushort_t* __restrict__ xf,
                                                      float* __restrict__ errb) {
  const int p = blockIdx.x, t = threadIdx.x;
  const int mf = t >> 6, lane = t & 63;
  const int lr = lane & 15, lg = lane >> 4;
  const int brow = p * 64 + mf * 16 + lr;
  const float* xr = x + (size_t)brow * K_DIM;
  float s = 0.0f;
  for (int kt = 0; kt < NKT; ++kt) {
    const int kbase = kt * 32 + lg * 8;
    float v[8];
    if (kbase + 8 <= K_DIM) {
      float4 a = *(const float4*)(xr + kbase);
      float4 b = *(const float4*)(xr + kbase + 4);
      v[0]=a.x; v[1]=a.y; v[2]=a.z; v[3]=a.w; v[4]=b.x; v[5]=b.y; v[6]=b.z; v[7]=b.w;
    } else {
#pragma unroll
      for (int j = 0; j < 8; ++j) v[j] = (kbase + j < K_DIM) ? xr[kbase + j] : 0.0f;
    }
    short8 hi, lo;
#pragma unroll
    for (int j = 0; j < 8; ++j) {
      s += fabsf(v[j]);
      ushort_t h = f2bf_rne(v[j]);
      float hf = __uint_as_float((unsigned)h << 16);
      ushort_t l = f2bf_rne(v[j] - hf);
      hi[j] = (short)h; lo[j] = (short)l;
    }
    size_t base = ((size_t)(p * NKT + kt) * 8 + mf) * 512 + lane * 8;
    *(short8*)&xf[base] = hi;
    *(short8*)&xf[base + 4 * 512] = lo;
  }
  s += __shfl_xor(s, 16, 64);
  s += __shfl_xor(s, 32, 64);
  if (lg == 0) errb[brow] = s * (1.02f / 65536.0f) + 0.125f;
}

// -------- fused layer1 GEMM + in-block exact fixup + layers 2+3 --------
// Output-stationary: block owns 64 b-rows x full N. r7-proven K-loop (plain
// __syncthreads dbuf; r8's asm pipeline regressed per m141/m190). Epilogue:
// bits -> LDS h1 words; borderline elems exactly recomputed in-block (bitwise
// sequential recipe); l2 popcount vs L2-resident w1b; l3 -> out. No h1b/global
// list round-trip, no separate fixup/l2l3 kernels.
__global__ __launch_bounds__(512, 2) void l1_fused_kernel(
    const ushort_t* __restrict__ xf, const ushort_t* __restrict__ sbf,
    const float* __restrict__ errb, const float* __restrict__ x,
    const u64* __restrict__ w0b, const u64* __restrict__ w1b,
    const u64* __restrict__ w2b, float* __restrict__ out) {
  extern __shared__ char smem[];
  const int p = blockIdx.x;
  const int t = threadIdx.x;
  const int wave = t >> 6, lane = t & 63;
  const int lr = lane & 15, lg = lane >> 4;
  const int b0 = p * 64;
  const int obase = wave * 144;

  const ushort_t* gA = xf + (size_t)p * NKT * (A_BYTES / 2);

  f32x4 acc[4][9];
#pragma unroll
  for (int mf = 0; mf < 4; ++mf)
#pragma unroll
    for (int nfl = 0; nfl < 9; ++nfl)
#pragma unroll
      for (int c = 0; c < 4; ++c) acc[mf][nfl][c] = 0.0f;

#define STAGE(BUFI, KT)                                                        \
  {                                                                            \
    char* dbuf = smem + (BUFI) * STEP_BYTES;                                   \
    _Pragma("unroll")                                                          \
    for (int i = 0; i < 10; ++i) {                                             \
      int s = wave * 10 + i;                                                   \
      const ushort_t* g = (s < 8)                                              \
          ? gA + (KT) * (A_BYTES / 2) + s * 512 + lane * 8                     \
          : sbf + (size_t)(KT) * (B_BYTES / 2) + (s - 8) * 512 + lane * 8;     \
      gload16(g, dbuf + s * 1024);                                             \
    }                                                                          \
  }

  STAGE(0, 0);
  __syncthreads();
  int cur = 0;
  for (int kt = 0; kt < NKT; ++kt) {
    if (kt + 1 < NKT) STAGE(cur ^ 1, kt + 1);
    const ushort_t* A = (const ushort_t*)(smem + cur * STEP_BYTES);
    const ushort_t* Bf = A + A_BYTES / 2;
    short8 ah[4], al[4];
#pragma unroll
    for (int mf = 0; mf < 4; ++mf) {
      ah[mf] = *(const short8*)&A[mf * 512 + lane * 8];
      al[mf] = *(const short8*)&A[(4 + mf) * 512 + lane * 8];
    }
#pragma unroll
    for (int nfl = 0; nfl < 9; ++nfl) {
      short8 bv = *(const short8*)&Bf[(wave * 9 + nfl) * 512 + lane * 8];
#pragma unroll
      for (int mf = 0; mf < 4; ++mf) {
        acc[mf][nfl] = __builtin_amdgcn_mfma_f32_16x16x32_bf16(ah[mf], bv, acc[mf][nfl], 0, 0, 0);
        acc[mf][nfl] = __builtin_amdgcn_mfma_f32_16x16x32_bf16(al[mf], bv, acc[mf][nfl], 0, 0, 0);
      }
    }
    __syncthreads();
    cur ^= 1;
  }
#undef STAGE

  // ---- epilogue LDS layout (reuses the 160 KB dynamic region) ----
  unsigned char* bits = (unsigned char*)smem;        // [64][1152]      0..73728
  u64*      hs   = (u64*)(smem + 73728);             // [64][17] h1     ..82432
  u64*      h2   = (u64*)(smem + 82432);             // [64][17]        ..91136
  unsigned* list = (unsigned*)(smem + 91136);        // FLAG_CAP u32    ..107520
  unsigned* lcnt = (unsigned*)(smem + 107520);
  unsigned* hsw  = (unsigned*)hs;                    // u32 view for atomicXor

  if (t == 0) *lcnt = 0;
  __syncthreads();

  float eb[4][4];
#pragma unroll
  for (int mf = 0; mf < 4; ++mf)
#pragma unroll
    for (int rg = 0; rg < 4; ++rg) eb[mf][rg] = errb[b0 + mf * 16 + lg * 4 + rg];

#pragma unroll
  for (int mf = 0; mf < 4; ++mf)
#pragma unroll
    for (int nfl = 0; nfl < 9; ++nfl)
#pragma unroll
      for (int rg = 0; rg < 4; ++rg) {
        int bl = mf * 16 + lg * 4 + rg;              // C/D: row = (lane>>4)*4 + reg
        int o  = obase + nfl * 16 + lr;              // C/D: col = lane & 15
        float lin = acc[mf][nfl][rg];
        unsigned abit = (lin >= 0.0f) ? 1u : 0u;
        bits[bl * 1152 + o] = (unsigned char)abit;
        if ((o < O_DIM) && (fabsf(lin) <= eb[mf][rg])) {
          unsigned idx = atomicAdd(lcnt, 1u);
          if (idx < FLAG_CAP)
            list[idx] = ((unsigned)bl << 12) | ((unsigned)o << 1) | abit;
        }
      }
  __syncthreads();

  // pack bits -> h1 words in LDS (pad bits = 1)
  for (int task = t; task < 64 * NWORDS; task += 512) {
    int row = task / NWORDS, w = task % NWORDS;
    u64 word = 0;
#pragma unroll
    for (int q = 0; q < 8; ++q) {
      u64 v = *(const u64*)&bits[row * 1152 + w * 64 + q * 8];
#pragma unroll
      for (int m = 0; m < 8; ++m)
        word |= ((v >> (8 * m)) & 1ull) << (q * 8 + m);
    }
    int rem = O_DIM - w * 64;
    if (rem < 64) word |= (~0ull << rem);
    hs[row * NWORDS + w] = word;
  }
  __syncthreads();

  // in-block exact recompute of flagged elements (bitwise = reference)
  {
    unsigned n = *lcnt; if (n > FLAG_CAP) n = FLAG_CAP;
    for (unsigned i = t; i < n; i += 512) {
      unsigned en = list[i];
      int bl = (int)(en >> 12), o = (int)((en >> 1) & 0x7ffu);
      unsigned abit = en & 1u;
      const float* xr = x + (size_t)(b0 + bl) * K_DIM;
      const u64* wr = w0b + (size_t)o * NWORDS;
      float a = 0.0f;
      for (int j = 0; j < 16; ++j) {    // k strictly ascending, single accumulator
        u64 wd = wr[j];
#pragma unroll
        for (int m = 0; m < 64; ++m) {
          float v = xr[j * 64 + m];
          unsigned neg = ((unsigned)(wd >> m) & 1u) ^ 1u;
          a += __uint_as_float(__float_as_uint(v) ^ (neg << 31));
        }
      }
      {
        u64 wd = wr[16];
        float v = xr[1024];
        unsigned neg = ((unsigned)wd & 1u) ^ 1u;
        a += __uint_as_float(__float_as_uint(v) ^ (neg << 31));
      }
      unsigned nb = (a >= 0.0f) ? 1u : 0u;
      if (nb != abit)
        atomicXor(&hsw[bl * 34 + (o >> 5)], 1u << (o & 31));
    }
  }
  __syncthreads();

  // layer 2: XOR+popcount vs w1b (exact ints; odd => never 0); 2-row ILP, lean regs
  {
    const int wv = t >> 6, l = t & 63;
    for (int oc = wv; oc < NWORDS; oc += 8) {
      int o = oc * 64 + l;
      bool valid = (o < O_DIM);
      int orow = valid ? o : (O_DIM - 1);
      u64 wb[NWORDS];
#pragma unroll
      for (int j = 0; j < NWORDS; ++j) wb[j] = w1b[(size_t)orow * NWORDS + j];
      for (int b = 0; b < 64; b += 2) {
        int p0 = 0, p1 = 0;
#pragma unroll
        for (int j = 0; j < NWORDS; ++j) {
          p0 += __popcll(hs[(b + 0) * NWORDS + j] ^ wb[j]);
          p1 += __popcll(hs[(b + 1) * NWORDS + j] ^ wb[j]);
        }
        u64 m0 = __ballot(valid ? (K_DIM - 2 * p0 >= 0) : true);   // pad bits = 1
        u64 m1 = __ballot(valid ? (K_DIM - 2 * p1 >= 0) : true);
        if (l == 0) h2[(b + 0) * NWORDS + oc] = m0;
        if (l == 1) h2[(b + 1) * NWORDS + oc] = m1;
      }
    }
  }
  __syncthreads();

  // layer 3: one neuron; sign -> {0,1}
  if (t < 64) {
    int pc = 0;
#pragma unroll
    for (int j = 0; j < NWORDS; ++j) pc += __popcll(h2[t * NWORDS + j] ^ w2b[j]);
    out[b0 + t] = ((K_DIM - 2 * pc) >= 0) ? 1.0f : 0.0f;
  }
}

extern "C" void kernel_launch(void* const* d_in, const int* in_sizes, int n_in,
                              void* d_out, int out_size, void* d_ws, size_t ws_size,
                              hipStream_t stream) {
  const float* x  = (const float*)d_in[0];
  const float* W0 = (const float*)d_in[1];
  const float* W1 = (const float*)d_in[2];
  const float* W2 = (const float*)d_in[3];
  float* out = (float*)d_out;

  char* ws = (char*)d_ws;
  u64*      w0b  = (u64*)(ws);                   //       0 .. 139776
  u64*      w1b  = (u64*)(ws + 139776);          // .. 279552
  u64*      w2b  = (u64*)(ws + 279552);          // .. 279808
  float*    errb = (float*)(ws + 279808);        // .. 345344
  ushort_t* sbf  = (ushort_t*)(ws + 345344);     // .. 2852096
  ushort_t* xf   = (ushort_t*)(ws + 2852096);    // .. 74155264

  static bool attr_set = false;
  if (!attr_set) {
    hipFuncSetAttribute((const void*)l1_fused_kernel,
                        hipFuncAttributeMaxDynamicSharedMemorySize, 2 * STEP_BYTES);
    attr_set = true;
  }

  pack_all_kernel<<<2 * O_DIM + 1, 256, 0, stream>>>(W0, W1, W2, w0b, w1b, w2b);
  prep_sbf_kernel<<<NKT * NFRAG / 4, 256, 0, stream>>>(W0, sbf);
  prep_xf_kernel<<<B_TOTAL / 64, 256, 0, stream>>>(x, xf, errb);
  l1_fused_kernel<<<B_TOTAL / 64, 512, 2 * STEP_BYTES, stream>>>(
      xf, sbf, errb, x, w0b, w1b, w2b, out);
}